// Round 5
// baseline (205.189 us; speedup 1.0000x reference)
//
#include <hip/hip_runtime.h>
#include <stdint.h>

typedef float  f32x4 __attribute__((ext_vector_type(4)));
typedef short  s16x8 __attribute__((ext_vector_type(8)));
typedef short  s16x4 __attribute__((ext_vector_type(4)));
typedef unsigned int uint32;

#define B_ 16
#define N_ 256
#define T_ 64
#define F_ 128
#define KT 32
#define NT 8   /* K tiles: 8*32 = 256 */

// LDS layout (bytes), UNPADDED 16x16 bf16 subtiles (512 B).
// X: all 8 k-tiles resident (64 KB). W: ONE 256l x 32k tile (16 KB).
// Total 81920 B -> exactly 2 blocks/CU in the 160 KiB pool.
#define SUBT 512
#define X_TILE_STR (16 * SUBT)              /* 8192 per k-tile */
#define X_OFF 0
#define W_OFF (NT * X_TILE_STR)             /* 65536 */
#define LDS_SZ (W_OFF + 32 * SUBT)          /* 81920 */

#define TRREAD(dst, addr) \
  asm volatile("ds_read_b64_tr_b16 %0, %1" : "=v"(dst) : "v"(addr))

#define LGKM_FENCE() asm volatile("s_waitcnt lgkmcnt(0)" ::: "memory")
#define BAR()                                    \
  do {                                           \
    LGKM_FENCE();                                \
    __builtin_amdgcn_s_barrier();                \
    asm volatile("" ::: "memory");               \
  } while (0)

__device__ __forceinline__ unsigned short f2bf(float f) {
  union { float f; unsigned int u; } v; v.f = f;
  unsigned int u = v.u;
  return (unsigned short)((u + 0x7fffu + ((u >> 16) & 1u)) >> 16);
}
__device__ __forceinline__ float bf2f(unsigned short h) {
  union { unsigned int u; float f; } v; v.u = ((unsigned int)h) << 16;
  return v.f;
}

// fwTb[c][l] = bf16(full_weight[l][c])  (256x256, lives in d_ws, L2-resident)
__global__ void wtrans_kernel(const float* __restrict__ fw,
                              unsigned short* __restrict__ fwTb) {
  int c = blockIdx.x;
  int l = threadIdx.x;
  fwTb[c * N_ + l] = f2bf(fw[l * N_ + c]);
}

__global__ __launch_bounds__(512, 4) void fused_kernel(
    const float* __restrict__ x,
    const int* __restrict__ entry,
    const int* __restrict__ job,
    const unsigned short* __restrict__ fwTb,
    float* __restrict__ out) {
  __shared__ __align__(16) char smem[LDS_SZ];
  const uint32 lds_u = (uint32)(uintptr_t)(&smem[0]);

  const int tid = threadIdx.x;
  const int bid = blockIdx.x;
  const int b = bid >> 6;
  const int t = bid & 63;

  const int wk  = tid & 31;   // this thread's k-column within every tile
  const int wlg = tid >> 5;   // this thread's 16-row l group (0..15)

  // ---- issue per-thread E/J id loads FIRST (oldest in vmcnt queue) ----
  int er[8], jr[8], jlr[16];
#pragma unroll
  for (int i = 0; i < 8; ++i) {
    er[i] = entry[(b * N_ + i * KT + wk) * T_ + t];
    jr[i] = job[(b * N_ + i * KT + wk) * T_ + t];
  }
#pragma unroll
  for (int i = 0; i < 16; ++i)
    jlr[i] = job[(b * N_ + wlg * 16 + i) * T_ + t];

  // ---- issue ALL X loads (8 tiles x 2 f32x4/thread; deep HBM queue) ----
  const int xk  = tid >> 4;          // 0..31 (k offset within a tile)
  const int xf0 = (tid & 15) << 3;   // 0,8,...,120
  const float* xsrc = x + ((b * N_ + xk) * T_ + t) * F_ + xf0;
#define XLD(i)                                                            \
  f32x4 q##i##a = *(const f32x4*)(xsrc + (i) * (KT * T_ * F_));           \
  f32x4 q##i##b = *(const f32x4*)(xsrc + (i) * (KT * T_ * F_) + 4);
  XLD(0) XLD(1) XLD(2) XLD(3) XLD(4) XLD(5) XLD(6) XLD(7)
#undef XLD

  // ---- pack ids into registers (waits only on the early id loads) ----
  uint32 ep0 = 0, ep1 = 0, jp0 = 0, jp1 = 0;
#pragma unroll
  for (int i = 0; i < 4; ++i) {
    ep0 |= ((uint32)(er[i] & 255)) << (8 * i);
    ep1 |= ((uint32)(er[i + 4] & 255)) << (8 * i);
    jp0 |= ((uint32)(jr[i] & 255)) << (8 * i);
    jp1 |= ((uint32)(jr[i + 4] & 255)) << (8 * i);
  }
  uint64_t jl80 = 0, jl81 = 0;
#pragma unroll
  for (int i = 0; i < 8; ++i) {
    jl80 |= ((uint64_t)(jlr[i] & 255)) << (8 * i);
    jl81 |= ((uint64_t)(jlr[i + 8] & 255)) << (8 * i);
  }

  // ---- W(0) gather from L2 (addresses from regs; X loads still in flight) --
  const uint32 wwr_base =
      (uint32)(((wk >> 4) * 16 + wlg) * SUBT + (wk & 15) * 32);
  {
    const int ev = (int)(ep0 & 255);
    const unsigned char gjk = (unsigned char)(jp0 & 255);
    const unsigned short* wrow = fwTb + ev * N_ + wlg * 16;
    s16x8 gv0 = *(const s16x8*)(wrow);
    s16x8 gv1 = *(const s16x8*)(wrow + 8);
    s16x8 m0, m1;
#pragma unroll
    for (int i = 0; i < 8; ++i) {
      const unsigned char a0 = (unsigned char)(jl80 >> (8 * i));
      const unsigned char a1 = (unsigned char)(jl81 >> (8 * i));
      m0[i] = (gjk != 0 && a0 == gjk) ? gv0[i] : (short)0;
      m1[i] = (gjk != 0 && a1 == gjk) ? gv1[i] : (short)0;
    }
    *(s16x8*)(smem + W_OFF + wwr_base) = m0;
    *(s16x8*)(smem + W_OFF + wwr_base + 16) = m1;
  }

  // ---- X convert + stage, all 8 tiles ----
  const uint32 xdst_in = (uint32)((((xk >> 4) * 8 + (xf0 >> 4)) * SUBT) +
                                  ((xk & 15) * 32) + ((xf0 & 15) * 2));
#define XST(i)                                                            \
  {                                                                       \
    s16x8 pk;                                                             \
    _Pragma("unroll") for (int _j = 0; _j < 4; ++_j) {                    \
      pk[_j]     = (short)f2bf(q##i##a[_j]);                              \
      pk[_j + 4] = (short)f2bf(q##i##b[_j]);                              \
    }                                                                     \
    *(s16x8*)(smem + X_OFF + (i) * X_TILE_STR + xdst_in) = pk;            \
  }
  XST(0) XST(1) XST(2) XST(3) XST(4) XST(5) XST(6) XST(7)
#undef XST
  BAR();  // X fully staged + W(0) ready

  const int lane = tid & 63;
  const int wid  = tid >> 6;
  const int wl   = wid & 3;   // wave's 64-l sub-tile (0..3)
  const int wf   = wid >> 2;  // wave's 64-f sub-tile (0..1)

  f32x4 acc[4][4];
#pragma unroll
  for (int i = 0; i < 4; ++i)
#pragma unroll
    for (int j = 0; j < 4; ++j) acc[i][j] = (f32x4){0.f, 0.f, 0.f, 0.f};

  for (int kt = 0; kt < NT; ++kt) {
    // ---- prefetch W(kt+1) gather into regs (ids from regs, no LDS dep;
    //      L2 latency hides under tr_read + MFMA) ----
    s16x8 pv0, pv1;
    unsigned char pjk = 0;
    if (kt + 1 < NT) {
      const uint32 esel = (kt + 1 < 4) ? ep0 : ep1;
      const uint32 jsel = (kt + 1 < 4) ? jp0 : jp1;
      const int sh = ((kt + 1) & 3) * 8;
      const int ev = (int)((esel >> sh) & 255);
      pjk = (unsigned char)((jsel >> sh) & 255);
      const unsigned short* wrow = fwTb + ev * N_ + wlg * 16;
      pv0 = *(const s16x8*)(wrow);
      pv1 = *(const s16x8*)(wrow + 8);
    }

    // ---- fragments: W from the single buffer, X from resident tile kt ----
    s16x4 ah[4][2], bh[4][2];
    {
      const uint32 wbase = lds_u + W_OFF + (uint32)(lane * 8);
      const uint32 xbase =
          lds_u + X_OFF + (uint32)(kt * X_TILE_STR) + (uint32)(lane * 8);
#pragma unroll
      for (int li = 0; li < 4; ++li) {
        TRREAD(ah[li][0], wbase + (uint32)((wl * 4 + li) * SUBT));
        TRREAD(ah[li][1], wbase + (uint32)((16 + wl * 4 + li) * SUBT));
      }
#pragma unroll
      for (int fi = 0; fi < 4; ++fi) {
        TRREAD(bh[fi][0], xbase + (uint32)((wf * 4 + fi) * SUBT));
        TRREAD(bh[fi][1], xbase + (uint32)((8 + wf * 4 + fi) * SUBT));
      }
      LGKM_FENCE();
      __builtin_amdgcn_sched_barrier(0);  // rule #18: nothing hoists above
    }
    // all waves' W reads are complete -> safe to overwrite W after this BAR
    if (kt + 1 < NT) BAR();

#pragma unroll
    for (int li = 0; li < 4; ++li) {
      s16x8 af = __builtin_shufflevector(ah[li][0], ah[li][1],
                                         0, 1, 2, 3, 4, 5, 6, 7);
#pragma unroll
      for (int fi = 0; fi < 4; ++fi) {
        s16x8 bf = __builtin_shufflevector(bh[fi][0], bh[fi][1],
                                           0, 1, 2, 3, 4, 5, 6, 7);
        acc[li][fi] =
            __builtin_amdgcn_mfma_f32_16x16x32_bf16(af, bf, acc[li][fi], 0, 0, 0);
      }
    }
    __builtin_amdgcn_sched_barrier(0);  // keep gather-wait/mask below MFMAs

    // ---- mask + write W(kt+1) into the (single) buffer ----
    if (kt + 1 < NT) {
      s16x8 m0, m1;
#pragma unroll
      for (int i = 0; i < 8; ++i) {
        const unsigned char a0 = (unsigned char)(jl80 >> (8 * i));
        const unsigned char a1 = (unsigned char)(jl81 >> (8 * i));
        m0[i] = (pjk != 0 && a0 == pjk) ? pv0[i] : (short)0;
        m1[i] = (pjk != 0 && a1 == pjk) ? pv1[i] : (short)0;
      }
      *(s16x8*)(smem + W_OFF + wwr_base) = m0;
      *(s16x8*)(smem + W_OFF + wwr_base + 16) = m1;
      BAR();  // W(kt+1) visible before next iteration's tr_reads
    }
  }

  // ---- epilogue: out = x + relu(y); residual from resident X LDS ----
  const int g4   = (lane >> 4) * 4;
  const int fcol = lane & 15;
#pragma unroll
  for (int li = 0; li < 4; ++li) {
    const int Lb = wl * 4 + li;  // 16-row l-block 0..15
    const uint32 rb = lds_u + X_OFF + (uint32)((Lb >> 1) * X_TILE_STR +
                       ((Lb & 1) * 8) * SUBT + lane * 8);
    s16x4 xr[4];
#pragma unroll
    for (int fi = 0; fi < 4; ++fi) {
      TRREAD(xr[fi], rb + (uint32)((wf * 4 + fi) * SUBT));
    }
    LGKM_FENCE();
    __builtin_amdgcn_sched_barrier(0);
    const int l0 = Lb * 16 + g4;
#pragma unroll
    for (int fi = 0; fi < 4; ++fi) {
      const int f = (wf * 4 + fi) * 16 + fcol;
      float* op = out + ((b * N_ + l0) * T_ + t) * F_ + f;
#pragma unroll
      for (int r = 0; r < 4; ++r) {
        float y = acc[li][fi][r];
        y = y > 0.f ? y : 0.f;
        op[r * (T_ * F_)] = bf2f((unsigned short)xr[fi][r]) + y;
      }
    }
  }
}

extern "C" void kernel_launch(void* const* d_in, const int* in_sizes, int n_in,
                              void* d_out, int out_size, void* d_ws,
                              size_t ws_size, hipStream_t stream) {
  (void)in_sizes; (void)n_in; (void)out_size; (void)ws_size;
  const float* x     = (const float*)d_in[0];
  const int*   entry = (const int*)d_in[1];
  const int*   job   = (const int*)d_in[2];
  // d_in[3] rackid unused; d_in[5..7] bias/gamma/beta dead in reference math
  const float* fw    = (const float*)d_in[4];
  unsigned short* fwTb = (unsigned short*)d_ws;  // 128 KB scratch

  hipLaunchKernelGGL(wtrans_kernel, dim3(N_), dim3(N_), 0, stream, fw, fwTb);
  hipLaunchKernelGGL(fused_kernel, dim3(B_ * T_), dim3(512), 0, stream,
                     x, entry, job, (const unsigned short*)fwTb, (float*)d_out);
}

// Round 6
// 81.688 us; speedup vs baseline: 2.5119x; 2.5119x over previous
//
#include <hip/hip_runtime.h>
#include <stdint.h>

typedef float  f32x4 __attribute__((ext_vector_type(4)));
typedef short  s16x8 __attribute__((ext_vector_type(8)));
typedef short  s16x4 __attribute__((ext_vector_type(4)));
typedef unsigned int uint32;

#define B_ 16
#define N_ 256
#define T_ 64
#define F_ 128
#define KT 32
#define NT 8   /* K tiles: 8*32 = 256 */

// LDS layout (bytes), UNPADDED 16x16 bf16 subtiles (512 B).
// X: all 8 k-tiles resident (64 KB). W: ONE 256l x 32k tile (16 KB).
// Total 81920 B -> exactly 2 blocks/CU in the 160 KiB pool.
#define SUBT 512
#define X_TILE_STR (16 * SUBT)              /* 8192 per k-tile */
#define X_OFF 0
#define W_OFF (NT * X_TILE_STR)             /* 65536 */
#define LDS_SZ (W_OFF + 32 * SUBT)          /* 81920 */

#define TRREAD(dst, addr) \
  asm volatile("ds_read_b64_tr_b16 %0, %1" : "=v"(dst) : "v"(addr))

#define LGKM_FENCE() asm volatile("s_waitcnt lgkmcnt(0)" ::: "memory")
#define BAR()                                    \
  do {                                           \
    LGKM_FENCE();                                \
    __builtin_amdgcn_s_barrier();                \
    asm volatile("" ::: "memory");               \
  } while (0)

__device__ __forceinline__ unsigned short f2bf(float f) {
  union { float f; unsigned int u; } v; v.f = f;
  unsigned int u = v.u;
  return (unsigned short)((u + 0x7fffu + ((u >> 16) & 1u)) >> 16);
}
__device__ __forceinline__ float bf2f(unsigned short h) {
  union { unsigned int u; float f; } v; v.u = ((unsigned int)h) << 16;
  return v.f;
}

// fwTb[c][l] = bf16(full_weight[l][c])  (256x256, lives in d_ws, L2-resident)
__global__ void wtrans_kernel(const float* __restrict__ fw,
                              unsigned short* __restrict__ fwTb) {
  int c = blockIdx.x;
  int l = threadIdx.x;
  fwTb[c * N_ + l] = f2bf(fw[l * N_ + c]);
}

// launch_bounds(512, 2): 256-VGPR cap. Compiler lands ~90-110 VGPRs (R4: 88)
// -> 4 waves/SIMD natural occupancy -> 2 blocks/CU (LDS 2x81920 = 160 KiB).
// DO NOT raise the 2nd arg: (512,4) empirically clamps to 64 VGPR -> spill.
__global__ __launch_bounds__(512, 2) void fused_kernel(
    const float* __restrict__ x,
    const int* __restrict__ entry,
    const int* __restrict__ job,
    const unsigned short* __restrict__ fwTb,
    float* __restrict__ out) {
  __shared__ __align__(16) char smem[LDS_SZ];
  const uint32 lds_u = (uint32)(uintptr_t)(&smem[0]);

  const int tid = threadIdx.x;
  const int bid = blockIdx.x;
  const int b = bid >> 6;
  const int t = bid & 63;

  const int wk  = tid & 31;   // this thread's k-column within every tile
  const int wlg = tid >> 5;   // this thread's 16-row l group (0..15)

  // ---- issue per-thread E/J id loads FIRST (oldest in vmcnt queue) ----
  int er[8], jr[8], jlr[16];
#pragma unroll
  for (int i = 0; i < 8; ++i) {
    er[i] = entry[(b * N_ + i * KT + wk) * T_ + t];
    jr[i] = job[(b * N_ + i * KT + wk) * T_ + t];
  }
#pragma unroll
  for (int i = 0; i < 16; ++i)
    jlr[i] = job[(b * N_ + wlg * 16 + i) * T_ + t];

  // ---- issue ALL X loads (8 tiles x 2 f32x4/thread; deep HBM queue) ----
  const int xk  = tid >> 4;          // 0..31 (k offset within a tile)
  const int xf0 = (tid & 15) << 3;   // 0,8,...,120
  const float* xsrc = x + ((b * N_ + xk) * T_ + t) * F_ + xf0;
#define XLD(i)                                                            \
  f32x4 q##i##a = *(const f32x4*)(xsrc + (i) * (KT * T_ * F_));           \
  f32x4 q##i##b = *(const f32x4*)(xsrc + (i) * (KT * T_ * F_) + 4);
  XLD(0) XLD(1) XLD(2) XLD(3) XLD(4) XLD(5) XLD(6) XLD(7)
#undef XLD

  // ---- pack ids into registers (waits only on the early id loads) ----
  uint32 ep0 = 0, ep1 = 0, jp0 = 0, jp1 = 0;
#pragma unroll
  for (int i = 0; i < 4; ++i) {
    ep0 |= ((uint32)(er[i] & 255)) << (8 * i);
    ep1 |= ((uint32)(er[i + 4] & 255)) << (8 * i);
    jp0 |= ((uint32)(jr[i] & 255)) << (8 * i);
    jp1 |= ((uint32)(jr[i + 4] & 255)) << (8 * i);
  }
  uint64_t jl80 = 0, jl81 = 0;
#pragma unroll
  for (int i = 0; i < 8; ++i) {
    jl80 |= ((uint64_t)(jlr[i] & 255)) << (8 * i);
    jl81 |= ((uint64_t)(jlr[i + 8] & 255)) << (8 * i);
  }

  // ---- W(0) gather from L2 (addresses from regs; X loads still in flight) --
  const uint32 wwr_base =
      (uint32)(((wk >> 4) * 16 + wlg) * SUBT + (wk & 15) * 32);
  {
    const int ev = (int)(ep0 & 255);
    const unsigned char gjk = (unsigned char)(jp0 & 255);
    const unsigned short* wrow = fwTb + ev * N_ + wlg * 16;
    s16x8 gv0 = *(const s16x8*)(wrow);
    s16x8 gv1 = *(const s16x8*)(wrow + 8);
    s16x8 m0, m1;
#pragma unroll
    for (int i = 0; i < 8; ++i) {
      const unsigned char a0 = (unsigned char)(jl80 >> (8 * i));
      const unsigned char a1 = (unsigned char)(jl81 >> (8 * i));
      m0[i] = (gjk != 0 && a0 == gjk) ? gv0[i] : (short)0;
      m1[i] = (gjk != 0 && a1 == gjk) ? gv1[i] : (short)0;
    }
    *(s16x8*)(smem + W_OFF + wwr_base) = m0;
    *(s16x8*)(smem + W_OFF + wwr_base + 16) = m1;
  }

  // ---- X convert + stage, all 8 tiles ----
  const uint32 xdst_in = (uint32)((((xk >> 4) * 8 + (xf0 >> 4)) * SUBT) +
                                  ((xk & 15) * 32) + ((xf0 & 15) * 2));
#define XST(i)                                                            \
  {                                                                       \
    s16x8 pk;                                                             \
    _Pragma("unroll") for (int _j = 0; _j < 4; ++_j) {                    \
      pk[_j]     = (short)f2bf(q##i##a[_j]);                              \
      pk[_j + 4] = (short)f2bf(q##i##b[_j]);                              \
    }                                                                     \
    *(s16x8*)(smem + X_OFF + (i) * X_TILE_STR + xdst_in) = pk;            \
  }
  XST(0) XST(1) XST(2) XST(3) XST(4) XST(5) XST(6) XST(7)
#undef XST
  BAR();  // X fully staged + W(0) ready

  const int lane = tid & 63;
  const int wid  = tid >> 6;
  const int wl   = wid & 3;   // wave's 64-l sub-tile (0..3)
  const int wf   = wid >> 2;  // wave's 64-f sub-tile (0..1)

  f32x4 acc[4][4];
#pragma unroll
  for (int i = 0; i < 4; ++i)
#pragma unroll
    for (int j = 0; j < 4; ++j) acc[i][j] = (f32x4){0.f, 0.f, 0.f, 0.f};

  for (int kt = 0; kt < NT; ++kt) {
    // ---- prefetch W(kt+1) gather into regs (ids from regs, no LDS dep;
    //      L2 latency hides under tr_read + MFMA) ----
    s16x8 pv0, pv1;
    unsigned char pjk = 0;
    if (kt + 1 < NT) {
      const uint32 esel = (kt + 1 < 4) ? ep0 : ep1;
      const uint32 jsel = (kt + 1 < 4) ? jp0 : jp1;
      const int sh = ((kt + 1) & 3) * 8;
      const int ev = (int)((esel >> sh) & 255);
      pjk = (unsigned char)((jsel >> sh) & 255);
      const unsigned short* wrow = fwTb + ev * N_ + wlg * 16;
      pv0 = *(const s16x8*)(wrow);
      pv1 = *(const s16x8*)(wrow + 8);
    }

    // ---- fragments: W from the single buffer, X from resident tile kt ----
    s16x4 ah[4][2], bh[4][2];
    {
      const uint32 wbase = lds_u + W_OFF + (uint32)(lane * 8);
      const uint32 xbase =
          lds_u + X_OFF + (uint32)(kt * X_TILE_STR) + (uint32)(lane * 8);
#pragma unroll
      for (int li = 0; li < 4; ++li) {
        TRREAD(ah[li][0], wbase + (uint32)((wl * 4 + li) * SUBT));
        TRREAD(ah[li][1], wbase + (uint32)((16 + wl * 4 + li) * SUBT));
      }
#pragma unroll
      for (int fi = 0; fi < 4; ++fi) {
        TRREAD(bh[fi][0], xbase + (uint32)((wf * 4 + fi) * SUBT));
        TRREAD(bh[fi][1], xbase + (uint32)((8 + wf * 4 + fi) * SUBT));
      }
      LGKM_FENCE();
      __builtin_amdgcn_sched_barrier(0);  // rule #18: nothing hoists above
    }
    // all waves' W reads are complete -> safe to overwrite W after this BAR
    if (kt + 1 < NT) BAR();

#pragma unroll
    for (int li = 0; li < 4; ++li) {
      s16x8 af = __builtin_shufflevector(ah[li][0], ah[li][1],
                                         0, 1, 2, 3, 4, 5, 6, 7);
#pragma unroll
      for (int fi = 0; fi < 4; ++fi) {
        s16x8 bf = __builtin_shufflevector(bh[fi][0], bh[fi][1],
                                           0, 1, 2, 3, 4, 5, 6, 7);
        acc[li][fi] =
            __builtin_amdgcn_mfma_f32_16x16x32_bf16(af, bf, acc[li][fi], 0, 0, 0);
      }
    }
    __builtin_amdgcn_sched_barrier(0);  // keep gather-wait/mask below MFMAs

    // ---- mask + write W(kt+1) into the (single) buffer ----
    if (kt + 1 < NT) {
      s16x8 m0, m1;
#pragma unroll
      for (int i = 0; i < 8; ++i) {
        const unsigned char a0 = (unsigned char)(jl80 >> (8 * i));
        const unsigned char a1 = (unsigned char)(jl81 >> (8 * i));
        m0[i] = (pjk != 0 && a0 == pjk) ? pv0[i] : (short)0;
        m1[i] = (pjk != 0 && a1 == pjk) ? pv1[i] : (short)0;
      }
      *(s16x8*)(smem + W_OFF + wwr_base) = m0;
      *(s16x8*)(smem + W_OFF + wwr_base + 16) = m1;
      BAR();  // W(kt+1) visible before next iteration's tr_reads
    }
  }

  // ---- epilogue: out = x + relu(y); residual from resident X LDS ----
  const int g4   = (lane >> 4) * 4;
  const int fcol = lane & 15;
#pragma unroll
  for (int li = 0; li < 4; ++li) {
    const int Lb = wl * 4 + li;  // 16-row l-block 0..15
    const uint32 rb = lds_u + X_OFF + (uint32)((Lb >> 1) * X_TILE_STR +
                       ((Lb & 1) * 8) * SUBT + lane * 8);
    s16x4 xr[4];
#pragma unroll
    for (int fi = 0; fi < 4; ++fi) {
      TRREAD(xr[fi], rb + (uint32)((wf * 4 + fi) * SUBT));
    }
    LGKM_FENCE();
    __builtin_amdgcn_sched_barrier(0);
    const int l0 = Lb * 16 + g4;
#pragma unroll
    for (int fi = 0; fi < 4; ++fi) {
      const int f = (wf * 4 + fi) * 16 + fcol;
      float* op = out + ((b * N_ + l0) * T_ + t) * F_ + f;
#pragma unroll
      for (int r = 0; r < 4; ++r) {
        float y = acc[li][fi][r];
        y = y > 0.f ? y : 0.f;
        op[r * (T_ * F_)] = bf2f((unsigned short)xr[fi][r]) + y;
      }
    }
  }
}

extern "C" void kernel_launch(void* const* d_in, const int* in_sizes, int n_in,
                              void* d_out, int out_size, void* d_ws,
                              size_t ws_size, hipStream_t stream) {
  (void)in_sizes; (void)n_in; (void)out_size; (void)ws_size;
  const float* x     = (const float*)d_in[0];
  const int*   entry = (const int*)d_in[1];
  const int*   job   = (const int*)d_in[2];
  // d_in[3] rackid unused; d_in[5..7] bias/gamma/beta dead in reference math
  const float* fw    = (const float*)d_in[4];
  unsigned short* fwTb = (unsigned short*)d_ws;  // 128 KB scratch

  hipLaunchKernelGGL(wtrans_kernel, dim3(N_), dim3(N_), 0, stream, fw, fwTb);
  hipLaunchKernelGGL(fused_kernel, dim3(B_ * T_), dim3(512), 0, stream,
                     x, entry, job, (const unsigned short*)fwTb, (float*)d_out);
}